// Round 1
// baseline (206.811 us; speedup 1.0000x reference)
//
#include <hip/hip_runtime.h>
#include <math.h>

#define HH 480
#define WW 640
#define HW (HH*WW)

// ---------------- K1: horizontal resample + p maps ----------------

__device__ __forceinline__ float sample1(const float* __restrict__ row, float x) {
    float x0 = floorf(x);
    float w1 = x - x0;
    int xi = (int)x0;
    float v0 = (xi >= 0 && xi < WW) ? row[xi] : 0.f;
    float v1 = (xi + 1 >= 0 && xi + 1 < WW) ? row[xi + 1] : 0.f;
    return v0 * (1.f - w1) + v1 * w1;
}

__global__ __launch_bounds__(256) void k_resample(
    const float* __restrict__ left, const float* __restrict__ right,
    const float* __restrict__ dispL, const float* __restrict__ dispR,
    float* __restrict__ rir, float* __restrict__ ril,
    float* __restrict__ pL, float* __restrict__ pR)
{
    int idx = blockIdx.x * blockDim.x + threadIdx.x;
    if (idx >= HW) return;
    int h = idx / WW;
    int w = idx - h * WW;
    float dL = dispL[idx];
    float dR = dispR[idx];
    float xl = (float)w - dL;   // sample right view at j - dispL
    float xr = (float)w + dR;   // sample left view  at j + dispR
    #pragma unroll
    for (int c = 0; c < 3; ++c) {
        rir[c*HW + idx] = sample1(right + c*HW + h*WW, xl);
        ril[c*HW + idx] = sample1(left  + c*HW + h*WW, xr);
    }
    float rdr = sample1(dispR + h*WW, xl);
    float rdl = sample1(dispL + h*WW, xr);
    pL[idx] = __expf(-0.6931f * fabsf(dL - rdr));
    pR[idx] = __expf(-0.6931f * fabsf(dR - rdl));
}

// ---------------- K2: 9x9 LCN + cost volumes ----------------

#define TB 16
#define PADL 4
#define TILE2 (TB + 2*PADL)   // 24

__global__ __launch_bounds__(256) void k_lcncost(
    const float* __restrict__ left, const float* __restrict__ right,
    const float* __restrict__ rir, const float* __restrict__ ril,
    float* __restrict__ costL, float* __restrict__ costR)
{
    __shared__ float tile[12][TILE2][TILE2];
    int tx = threadIdx.x, ty = threadIdx.y;
    int tid = ty * TB + tx;
    int gx0 = blockIdx.x * TB, gy0 = blockIdx.y * TB;

    // arrays: 0-2 left, 3-5 right, 6-8 rir, 9-11 ril
    for (int e = tid; e < 12 * TILE2 * TILE2; e += 256) {
        int a  = e / (TILE2 * TILE2);
        int rem = e - a * (TILE2 * TILE2);
        int r  = rem / TILE2;
        int cc = rem - r * TILE2;
        int gy = gy0 + r - PADL;
        int gx = gx0 + cc - PADL;
        float v = 0.f;
        if (gy >= 0 && gy < HH && gx >= 0 && gx < WW) {
            int img = a / 3;
            int ch  = a - img * 3;
            const float* s = (img == 0) ? left : (img == 1) ? right : (img == 2) ? rir : ril;
            v = s[ch*HW + gy*WW + gx];
        }
        ((float*)tile)[e] = v;
    }
    __syncthreads();

    auto lcn_std = [&](int a, float& lcn, float& stdv) {
        float s = 0.f, s2 = 0.f;
        #pragma unroll
        for (int dy = 0; dy < 9; ++dy) {
            #pragma unroll
            for (int dx = 0; dx < 9; ++dx) {
                float v = tile[a][ty + dy][tx + dx];
                s += v;
                s2 += v * v;
            }
        }
        float mean = s * (1.f/81.f);
        float msq  = s2 * (1.f/81.f);
        float var  = msq - mean * mean;
        stdv = sqrtf(fmaxf(var, 0.f)) * (81.f/80.f);
        lcn  = (tile[a][ty + PADL][tx + PADL] - mean) / (stdv + 1e-5f);
    };

    int idx = (gy0 + ty) * WW + gx0 + tx;
    #pragma unroll
    for (int c = 0; c < 3; ++c) {
        float lcnL, stdL, lcnRIR, stdDummy;
        lcn_std(c,     lcnL,   stdL);
        lcn_std(6 + c, lcnRIR, stdDummy);
        costL[c*HW + idx] = fabsf((lcnL - lcnRIR) * stdL);
        float lcnR, stdR, lcnRIL;
        lcn_std(3 + c, lcnR,   stdR);
        lcn_std(9 + c, lcnRIL, stdDummy);
        costR[c*HW + idx] = fabsf((lcnR - lcnRIL) * stdR);
    }
}

// ---------------- K3: 12x12 ASW + losses + reduction ----------------

#define PADA 6
#define TILE3 (TB + 11)   // 27

__global__ __launch_bounds__(256) void k_asw_reduce(
    const float* __restrict__ left, const float* __restrict__ right,
    const float* __restrict__ rir, const float* __restrict__ ril,
    const float* __restrict__ costL, const float* __restrict__ costR,
    const float* __restrict__ pL, const float* __restrict__ pR,
    float* __restrict__ acc)
{
    __shared__ float tile[9][TILE3][TILE3];
    __shared__ float red[4][6];
    int tx = threadIdx.x, ty = threadIdx.y;
    int tid = ty * TB + tx;
    int gx0 = blockIdx.x * TB, gy0 = blockIdx.y * TB;

    // arrays: 0-2 guide(left), 3-5 costL, 6-8 costR
    for (int e = tid; e < 9 * TILE3 * TILE3; e += 256) {
        int a  = e / (TILE3 * TILE3);
        int rem = e - a * (TILE3 * TILE3);
        int r  = rem / TILE3;
        int cc = rem - r * TILE3;
        int gy = gy0 + r - PADA;
        int gx = gx0 + cc - PADA;
        float v = 0.f;
        if (gy >= 0 && gy < HH && gx >= 0 && gx < WW) {
            const float* s = (a < 3) ? left : (a < 6) ? costL : costR;
            int ch = (a < 3) ? a : (a < 6) ? (a - 3) : (a - 6);
            v = s[ch*HW + gy*WW + gx];
        }
        ((float*)tile)[e] = v;
    }
    __syncthreads();

    float g[3], wg[3] = {0.f, 0.f, 0.f}, caL[3] = {0.f, 0.f, 0.f}, caR[3] = {0.f, 0.f, 0.f};
    #pragma unroll
    for (int c = 0; c < 3; ++c) g[c] = tile[c][ty + PADA][tx + PADA];

    #pragma unroll 4
    for (int dy = 0; dy < 12; ++dy) {
        #pragma unroll
        for (int dx = 0; dx < 12; ++dx) {
            #pragma unroll
            for (int c = 0; c < 3; ++c) {
                float gs = tile[c][ty + dy][tx + dx];
                float t = __expf(-0.5f * fabsf(g[c] - gs));
                wg[c]  += t;
                caL[c] += t * tile[3 + c][ty + dy][tx + dx];
                caR[c] += t * tile[6 + c][ty + dy][tx + dx];
            }
        }
    }

    int idx = (gy0 + ty) * WW + gx0 + tx;
    float sL = 0.f, sR = 0.f;
    #pragma unroll
    for (int c = 0; c < 3; ++c) {
        float aswL = caL[c] / wg[c];
        float photoL = fabsf(g[c] - rir[c*HW + idx]);
        sL += 0.5f * photoL + 0.5f * aswL;
        float aswR = caR[c] / wg[c];
        float photoR = fabsf(right[c*HW + idx] - ril[c*HW + idx]);
        sR += 0.5f * photoR + 0.5f * aswR;
    }
    float pl = pL[idx], pr = pR[idx];
    float mL = (pl > 0.5f) ? 1.f : 0.f;
    float mR = (pr > 0.5f) ? 1.f : 0.f;
    float vals[6];
    vals[0] = sL * mL;
    vals[1] = mL;
    vals[2] = sR * mR;
    vals[3] = mR;
    vals[4] = log1pf(__expf(1.f - 2.f * pl));
    vals[5] = log1pf(__expf(1.f - 2.f * pr));

    int lane = tid & 63, wave = tid >> 6;
    #pragma unroll
    for (int k = 0; k < 6; ++k) {
        float v = vals[k];
        #pragma unroll
        for (int off = 32; off > 0; off >>= 1) v += __shfl_down(v, off);
        if (lane == 0) red[wave][k] = v;
    }
    __syncthreads();
    if (tid == 0) {
        #pragma unroll
        for (int k = 0; k < 6; ++k)
            atomicAdd(&acc[k], red[0][k] + red[1][k] + red[2][k] + red[3][k]);
    }
}

// ---------------- K4: finalize ----------------

__global__ void k_final(const float* __restrict__ acc, const float* __restrict__ weight,
                        float* __restrict__ out)
{
    float S1 = acc[0], M1 = acc[1], S2 = acc[2], M2 = acc[3], C1 = acc[4], C2 = acc[5];
    float loss_valid = S1 / (3.f * M1 + 1e-6f) + S2 / (3.f * M2 + 1e-6f);
    float loss_invalid = (C1 + C2) * (1.f / (float)HW);
    out[0] = weight[0] * (0.9f * loss_valid + 0.1f * loss_invalid);
}

// ---------------- launch ----------------

extern "C" void kernel_launch(void* const* d_in, const int* in_sizes, int n_in,
                              void* d_out, int out_size, void* d_ws, size_t ws_size,
                              hipStream_t stream)
{
    const float* left  = (const float*)d_in[0];
    const float* right = (const float*)d_in[1];
    const float* dispL = (const float*)d_in[2];
    const float* dispR = (const float*)d_in[3];
    // d_in[4] = dispmap_gt (unused), d_in[5] = brk (unused)
    const float* weight = (const float*)d_in[6];

    float* ws    = (float*)d_ws;
    float* acc   = ws;              // 8 floats (6 used)
    float* rir   = ws + 8;          // 3*HW
    float* ril   = rir + 3*HW;      // 3*HW
    float* pL    = ril + 3*HW;      // HW
    float* pR    = pL + HW;         // HW
    float* costL = pR + HW;         // 3*HW
    float* costR = costL + 3*HW;    // 3*HW

    hipMemsetAsync(acc, 0, 8 * sizeof(float), stream);

    k_resample<<<(HW + 255) / 256, 256, 0, stream>>>(left, right, dispL, dispR, rir, ril, pL, pR);

    dim3 blk(TB, TB);
    dim3 grd(WW / TB, HH / TB);
    k_lcncost<<<grd, blk, 0, stream>>>(left, right, rir, ril, costL, costR);
    k_asw_reduce<<<grd, blk, 0, stream>>>(left, right, rir, ril, costL, costR, pL, pR, acc);
    k_final<<<1, 1, 0, stream>>>(acc, weight, (float*)d_out);
}

// Round 2
// 173.410 us; speedup vs baseline: 1.1926x; 1.1926x over previous
//
#include <hip/hip_runtime.h>
#include <math.h>

#define HH 480
#define WW 640
#define HW (HH*WW)

// ---------------- K1: horizontal resample + p maps ----------------

__device__ __forceinline__ float sample1(const float* __restrict__ row, float x) {
    float x0 = floorf(x);
    float w1 = x - x0;
    int xi = (int)x0;
    float v0 = (xi >= 0 && xi < WW) ? row[xi] : 0.f;
    float v1 = (xi + 1 >= 0 && xi + 1 < WW) ? row[xi + 1] : 0.f;
    return v0 * (1.f - w1) + v1 * w1;
}

__global__ __launch_bounds__(256) void k_resample(
    const float* __restrict__ left, const float* __restrict__ right,
    const float* __restrict__ dispL, const float* __restrict__ dispR,
    float* __restrict__ rir, float* __restrict__ ril,
    float* __restrict__ pL, float* __restrict__ pR)
{
    int idx = blockIdx.x * blockDim.x + threadIdx.x;
    if (idx >= HW) return;
    int h = idx / WW;
    int w = idx - h * WW;
    float dL = dispL[idx];
    float dR = dispR[idx];
    float xl = (float)w - dL;   // sample right view at j - dispL
    float xr = (float)w + dR;   // sample left view  at j + dispR
    #pragma unroll
    for (int c = 0; c < 3; ++c) {
        rir[c*HW + idx] = sample1(right + c*HW + h*WW, xl);
        ril[c*HW + idx] = sample1(left  + c*HW + h*WW, xr);
    }
    float rdr = sample1(dispR + h*WW, xl);
    float rdl = sample1(dispL + h*WW, xr);
    pL[idx] = __expf(-0.6931f * fabsf(dL - rdr));
    pR[idx] = __expf(-0.6931f * fabsf(dR - rdl));
}

// ---------------- K2: 9x9 LCN (separable) + cost, one side per blockIdx.z ----------------
// block 32x8, tile rows 16 (8+2*4), cols 40 (32+2*4)

__global__ __launch_bounds__(256) void k_lcncost(
    const float* __restrict__ left, const float* __restrict__ right,
    const float* __restrict__ rir, const float* __restrict__ ril,
    float* __restrict__ costL, float* __restrict__ costR)
{
    __shared__ float raw[6][16][40];   // 15360 B
    __shared__ float hs [6][16][32];   // 12288 B
    __shared__ float hs2[6][16][32];   // 12288 B
    int tx = threadIdx.x, ty = threadIdx.y;
    int tid = ty * 32 + tx;
    int gx0 = blockIdx.x * 32, gy0 = blockIdx.y * 8;
    const float* __restrict__ imgA = blockIdx.z ? right : left;   // real image (std source)
    const float* __restrict__ imgB = blockIdx.z ? ril   : rir;    // reconstruction
    float* __restrict__ out = blockIdx.z ? costR : costL;

    // stage raw: arrays 0-2 imgA ch, 3-5 imgB ch, zero-padded
    for (int e = tid; e < 6*16*40; e += 256) {
        int a   = e / (16*40);
        int rem = e - a * (16*40);
        int r   = rem / 40;
        int x   = rem - r * 40;
        int gy = gy0 + r - 4, gx = gx0 + x - 4;
        float v = 0.f;
        if ((unsigned)gy < (unsigned)HH && (unsigned)gx < (unsigned)WW) {
            const float* s = (a < 3) ? imgA : imgB;
            int ch = (a < 3) ? a : a - 3;
            v = s[ch*HW + gy*WW + gx];
        }
        ((float*)raw)[e] = v;
    }
    __syncthreads();

    // horizontal 9-tap sums of v and v^2
    for (int e = tid; e < 6*16*32; e += 256) {
        int a   = e / (16*32);
        int rem = e - a * (16*32);
        int r   = rem / 32;
        int x   = rem - r * 32;
        float s = 0.f, s2 = 0.f;
        #pragma unroll
        for (int dx = 0; dx < 9; ++dx) {
            float v = raw[a][r][x + dx];
            s += v;
            s2 = fmaf(v, v, s2);
        }
        ((float*)hs)[e]  = s;
        ((float*)hs2)[e] = s2;
    }
    __syncthreads();

    // vertical 9-tap + LCN + cost
    int idx = (gy0 + ty) * WW + gx0 + tx;
    #pragma unroll
    for (int c = 0; c < 3; ++c) {
        float SA = 0.f, SA2 = 0.f, SB = 0.f, SB2 = 0.f;
        #pragma unroll
        for (int dy = 0; dy < 9; ++dy) {
            SA  += hs [c][ty + dy][tx];
            SA2 += hs2[c][ty + dy][tx];
            SB  += hs [3 + c][ty + dy][tx];
            SB2 += hs2[3 + c][ty + dy][tx];
        }
        float meanA = SA * (1.f/81.f);
        float stdA  = sqrtf(fmaxf(SA2 * (1.f/81.f) - meanA * meanA, 0.f)) * (81.f/80.f);
        float lcnA  = (raw[c][ty + 4][tx + 4] - meanA) / (stdA + 1e-5f);
        float meanB = SB * (1.f/81.f);
        float stdB  = sqrtf(fmaxf(SB2 * (1.f/81.f) - meanB * meanB, 0.f)) * (81.f/80.f);
        float lcnB  = (raw[3 + c][ty + 4][tx + 4] - meanB) / (stdB + 1e-5f);
        out[c*HW + idx] = fabsf((lcnA - lcnB) * stdA);
    }
}

// ---------------- K3: 12x12 ASW + losses + reduction ----------------
// block 32x8, tile rows 19 (8+11), cols 43 (32+11); float4 = (guide, costL, costR, 0)

__global__ __launch_bounds__(256) void k_asw_reduce(
    const float* __restrict__ left, const float* __restrict__ right,
    const float* __restrict__ rir, const float* __restrict__ ril,
    const float* __restrict__ costL, const float* __restrict__ costR,
    const float* __restrict__ pL, const float* __restrict__ pR,
    float* __restrict__ acc)
{
    __shared__ float4 tile[3][19][43];   // 39216 B
    __shared__ float red[4][6];
    int tx = threadIdx.x, ty = threadIdx.y;
    int tid = ty * 32 + tx;
    int gx0 = blockIdx.x * 32, gy0 = blockIdx.y * 8;

    for (int e = tid; e < 3*19*43; e += 256) {
        int c   = e / (19*43);
        int rem = e - c * (19*43);
        int r   = rem / 43;
        int x   = rem - r * 43;
        int gy = gy0 + r - 6, gx = gx0 + x - 6;
        float4 v = make_float4(0.f, 0.f, 0.f, 0.f);
        if ((unsigned)gy < (unsigned)HH && (unsigned)gx < (unsigned)WW) {
            int o = c*HW + gy*WW + gx;
            v.x = left[o];
            v.y = costL[o];
            v.z = costR[o];
        }
        ((float4*)tile)[e] = v;
    }
    __syncthreads();

    float g[3];
    #pragma unroll
    for (int c = 0; c < 3; ++c) g[c] = tile[c][ty + 6][tx + 6].x;
    float wg[3] = {0.f,0.f,0.f}, aL[3] = {0.f,0.f,0.f}, aR[3] = {0.f,0.f,0.f};

    for (int dy = 0; dy < 12; ++dy) {
        #pragma unroll
        for (int dx = 0; dx < 12; ++dx) {
            #pragma unroll
            for (int c = 0; c < 3; ++c) {
                float4 v = tile[c][ty + dy][tx + dx];
                float t = __expf(-0.5f * fabsf(g[c] - v.x));
                wg[c] += t;
                aL[c] = fmaf(t, v.y, aL[c]);
                aR[c] = fmaf(t, v.z, aR[c]);
            }
        }
    }

    int idx = (gy0 + ty) * WW + gx0 + tx;
    float sL = 0.f, sR = 0.f;
    #pragma unroll
    for (int c = 0; c < 3; ++c) {
        float aswL = aL[c] / wg[c];
        float photoL = fabsf(g[c] - rir[c*HW + idx]);
        sL += 0.5f * photoL + 0.5f * aswL;
        float aswR = aR[c] / wg[c];
        float photoR = fabsf(right[c*HW + idx] - ril[c*HW + idx]);
        sR += 0.5f * photoR + 0.5f * aswR;
    }
    float pl = pL[idx], pr = pR[idx];
    float mL = (pl > 0.5f) ? 1.f : 0.f;
    float mR = (pr > 0.5f) ? 1.f : 0.f;
    float vals[6];
    vals[0] = sL * mL;
    vals[1] = mL;
    vals[2] = sR * mR;
    vals[3] = mR;
    vals[4] = log1pf(__expf(1.f - 2.f * pl));
    vals[5] = log1pf(__expf(1.f - 2.f * pr));

    int lane = tid & 63, wave = tid >> 6;
    #pragma unroll
    for (int k = 0; k < 6; ++k) {
        float v = vals[k];
        #pragma unroll
        for (int off = 32; off > 0; off >>= 1) v += __shfl_down(v, off);
        if (lane == 0) red[wave][k] = v;
    }
    __syncthreads();
    if (tid == 0) {
        #pragma unroll
        for (int k = 0; k < 6; ++k)
            atomicAdd(&acc[k], red[0][k] + red[1][k] + red[2][k] + red[3][k]);
    }
}

// ---------------- K4: finalize ----------------

__global__ void k_final(const float* __restrict__ acc, const float* __restrict__ weight,
                        float* __restrict__ out)
{
    float S1 = acc[0], M1 = acc[1], S2 = acc[2], M2 = acc[3], C1 = acc[4], C2 = acc[5];
    float loss_valid = S1 / (3.f * M1 + 1e-6f) + S2 / (3.f * M2 + 1e-6f);
    float loss_invalid = (C1 + C2) * (1.f / (float)HW);
    out[0] = weight[0] * (0.9f * loss_valid + 0.1f * loss_invalid);
}

// ---------------- launch ----------------

extern "C" void kernel_launch(void* const* d_in, const int* in_sizes, int n_in,
                              void* d_out, int out_size, void* d_ws, size_t ws_size,
                              hipStream_t stream)
{
    const float* left  = (const float*)d_in[0];
    const float* right = (const float*)d_in[1];
    const float* dispL = (const float*)d_in[2];
    const float* dispR = (const float*)d_in[3];
    // d_in[4] = dispmap_gt (unused), d_in[5] = brk (unused)
    const float* weight = (const float*)d_in[6];

    float* ws    = (float*)d_ws;
    float* acc   = ws;              // 8 floats (6 used)
    float* rir   = ws + 8;          // 3*HW
    float* ril   = rir + 3*HW;      // 3*HW
    float* pL    = ril + 3*HW;      // HW
    float* pR    = pL + HW;         // HW
    float* costL = pR + HW;         // 3*HW
    float* costR = costL + 3*HW;    // 3*HW

    hipMemsetAsync(acc, 0, 8 * sizeof(float), stream);

    k_resample<<<(HW + 255) / 256, 256, 0, stream>>>(left, right, dispL, dispR, rir, ril, pL, pR);

    dim3 blk(32, 8);
    dim3 grd2(WW / 32, HH / 8, 2);
    k_lcncost<<<grd2, blk, 0, stream>>>(left, right, rir, ril, costL, costR);
    dim3 grd3(WW / 32, HH / 8);
    k_asw_reduce<<<grd3, blk, 0, stream>>>(left, right, rir, ril, costL, costR, pL, pR, acc);
    k_final<<<1, 1, 0, stream>>>(acc, weight, (float*)d_out);
}